// Round 15
// baseline (311.739 us; speedup 1.0000x reference)
//
#include <hip/hip_runtime.h>

// ---------------------------------------------------------------------------
// BiMambaEncoderBlock on MI355X (gfx950). fp32 accumulate, bf16 intermediates.
// B=2, S=1024, D_MODEL=256, D_INNER=512, D_STATE=64, DT_RANK=16, D_CONV=4.
// Round 15: 32 scan chunks of 32 (was 16x64) -> pass2 8 waves/SIMD (was 4,
// Occ 38%); chunk handoff states Bch stored bf16 to keep ws ~36 MiB.
// Everything else identical to round 14.
// ---------------------------------------------------------------------------

typedef unsigned short u16;
typedef short bf16x8 __attribute__((ext_vector_type(8)));   // 8 bf16 = 4 VGPRs
typedef float f32x4  __attribute__((ext_vector_type(4)));

#define MFMA(a, b, c) __builtin_amdgcn_mfma_f32_16x16x32_bf16((a), (b), (c), 0, 0, 0)
#if __has_builtin(__builtin_amdgcn_exp2f)
#define EXP2(x) __builtin_amdgcn_exp2f(x)
#else
#define EXP2(x) exp2f(x)
#endif
static constexpr float LOG2E = 1.44269504088896340736f;

static constexpr int ROWS = 2048;   // B*S
static constexpr int DM   = 256;    // d_model
static constexpr int DI   = 512;    // d_inner
static constexpr int NXZ  = 1024;   // 2*d_inner
static constexpr int DS   = 64;     // d_state
static constexpr int NCH  = 32;     // scan chunks
static constexpr int CHL  = 32;     // chunk length

__device__ __forceinline__ float bf2f(u16 u) {
  union { unsigned u32; float f; } v; v.u32 = ((unsigned)u) << 16; return v.f;
}
__device__ __forceinline__ u16 f2bf(float f) {
  union { float f; unsigned u; } v; v.f = f;
  unsigned r = v.u + 0x7FFFu + ((v.u >> 16) & 1u);   // RNE (finite inputs)
  return (u16)(r >> 16);
}
__device__ __forceinline__ float ldx(const void* p, size_t i, int f32) {
  return f32 ? ((const float*)p)[i] : bf2f(((const u16*)p)[i]);
}
// wave-uniform dtype detect: even u16s of f32 data are uniform-random bf16
// patterns (P[all 64 within +-1024] ~ 4e-18); bf16 N(0,1) data always passes.
__device__ __forceinline__ int detect_f32(const void* xp) {
  const u16* p = (const u16*)xp;
  int lane = threadIdx.x & 63;
  float v = bf2f(p[lane * 2]);
  int bad = !(v > -1024.0f && v < 1024.0f);
  return (__ballot(bad) != 0ull) ? 1 : 0;
}

// ---- workspace layout (bytes) ----
static constexpr size_t XZ_OFF   = 0;          // bf16 [2][2048][1024]
static constexpr size_t XC_OFF   = 8388608;    // bf16 [4096][512]  (row=dirb*1024+t)
static constexpr size_t DTIN_OFF = 12582912;   // f32  [4096][16]   dt-proj inputs
static constexpr size_t BC_OFF   = 12845056;   // f32  [4096][128]  B(0:64) C(64:128)
static constexpr size_t DTT_OFF  = 14942208;   // bf16 [4][512][1024]  dt  (dirb,d,t)
static constexpr size_t DXT_OFF  = 19136512;   // bf16 [4][512][1024]  dt*xc
static constexpr size_t Y_OFF    = 23330816;   // bf16 [4096][512]
static constexpr size_t SCH_OFF  = 27525120;   // f32  [2048][31]      sum(dt) per chunk
static constexpr size_t BCH_OFF  = 27779072;   // bf16 [2048][31][64]  chunk h_end -> h_in
static constexpr size_t WB_OFF   = 35905536;   // bf16 weights
// converted-weight region (element offsets within WB):
static constexpr int WB_IWF = 0;        // f_in_w  [1024][256]
static constexpr int WB_IWB = 262144;   // b_in_w  [1024][256]
static constexpr int WB_XPF = 524288;   // f_xproj [144][512]
static constexpr int WB_XPB = 598016;   // b_xproj [144][512]
static constexpr int WB_OWF = 671744;   // f_out_w [256][512]
static constexpr int WB_OWB = 802816;   // b_out_w [256][512]
static constexpr int WB_W2  = 933888;   // w2      [256][256]
static constexpr int WB_DWF = 999424;   // f_dt_w  [512][16]
static constexpr int WB_DWB = 1007616;  // b_dt_w  [512][16]
static constexpr int WB_TOT = 1015808;
// total ws ≈ 36.2 MiB (< 39.2 MiB proven in round 7)

// ---------------------------------------------------------------------------
// K0b: convert all GEMM weights to bf16 into ws (identity if already bf16).
// ---------------------------------------------------------------------------
__global__ __launch_bounds__(256) void convert_kernel(
    const void* __restrict__ x,
    const void* __restrict__ f_iw, const void* __restrict__ b_iw,
    const void* __restrict__ f_xp, const void* __restrict__ b_xp,
    const void* __restrict__ f_ow, const void* __restrict__ b_ow,
    const void* __restrict__ w2,   const void* __restrict__ f_dw,
    const void* __restrict__ b_dw, u16* __restrict__ wb) {
  int f32 = detect_f32(x);
  int i = blockIdx.x * 256 + threadIdx.x;
  if (i >= WB_TOT) return;
  const void* src; int off;
  if      (i < WB_IWB) { src = f_iw; off = i - WB_IWF; }
  else if (i < WB_XPF) { src = b_iw; off = i - WB_IWB; }
  else if (i < WB_XPB) { src = f_xp; off = i - WB_XPF; }
  else if (i < WB_OWF) { src = b_xp; off = i - WB_XPB; }
  else if (i < WB_OWB) { src = f_ow; off = i - WB_OWF; }
  else if (i < WB_W2)  { src = b_ow; off = i - WB_OWB; }
  else if (i < WB_DWF) { src = w2;   off = i - WB_W2;  }
  else if (i < WB_DWB) { src = f_dw; off = i - WB_DWF; }
  else                 { src = b_dw; off = i - WB_DWB; }
  wb[i] = f2bf(ldx(src, (size_t)off, f32));
}

// ---------------------------------------------------------------------------
// K2: fused LayerNorm1 + in-projection (MFMA).
// xz[dir][m][:] = LN(x[srow(m)]) @ in_w.T  (K=256).
// grid (128, 4, 2), block 256. Wave: 16m x 64n.
// ---------------------------------------------------------------------------
__global__ __launch_bounds__(256) void inproj_ln1_kernel(
    const void* __restrict__ x, const void* __restrict__ g,
    const void* __restrict__ b, const u16* __restrict__ wb,
    u16* __restrict__ xz) {
  int f32 = detect_f32(x);
  int dir  = blockIdx.z;
  int tid  = threadIdx.x;
  int wave = tid >> 6, lane = tid & 63;
  int m0 = blockIdx.x * 16;
  int n0 = blockIdx.y * 256 + wave * 64;
  int bb0 = m0 >> 10;
  __shared__ float S1[16][17], S2[16][17];
  __shared__ float mu_s[16], rs_s[16];
  __shared__ float g_s[DM], b_s[DM];
  // stage 1: LN stats for the block's 16 source rows
  {
    int r = tid & 15, ch = tid >> 4;           // row, 16-col chunk
    int mr = m0 + r, tpos = mr & 1023;
    int srow_r = dir ? (bb0 * 1024 + (1023 - tpos)) : mr;
    float s = 0.0f, s2 = 0.0f;
#pragma unroll
    for (int i = 0; i < 16; ++i) {
      float v = ldx(x, (size_t)srow_r * DM + ch * 16 + i, f32);
      s += v; s2 += v * v;
    }
    S1[r][ch] = s; S2[r][ch] = s2;
    g_s[tid] = ldx(g, tid, f32);
    b_s[tid] = ldx(b, tid, f32);
  }
  __syncthreads();
  if (tid < 16) {
    float a = 0.0f, q = 0.0f;
#pragma unroll
    for (int c = 0; c < 16; ++c) { a += S1[tid][c]; q += S2[tid][c]; }
    float m_ = a * (1.0f / DM);
    float v_ = q * (1.0f / DM) - m_ * m_;
    mu_s[tid] = m_;
    rs_s[tid] = rsqrtf(v_ + 1e-5f);
  }
  __syncthreads();
  // stage 2: MFMA with normalized A-fragment
  int lm = lane & 15, quad = lane >> 4;
  const short* W = (const short*)(wb + (dir ? WB_IWB : WB_IWF));
  int m = m0 + lm;
  int tpos = m & 1023;
  int srow = dir ? (bb0 * 1024 + (1023 - tpos)) : m;
  float mu = mu_s[lm], rs = rs_s[lm];
  f32x4 acc[4] = {};
  for (int k0 = 0; k0 < DM; k0 += 32) {
    int k = k0 + quad * 8;
    float xv[8];
    if (f32) {
      f32x4 x0 = *(const f32x4*)((const float*)x + (size_t)srow * DM + k);
      f32x4 x1 = *(const f32x4*)((const float*)x + (size_t)srow * DM + k + 4);
#pragma unroll
      for (int j = 0; j < 4; ++j) { xv[j] = x0[j]; xv[4 + j] = x1[j]; }
    } else {
      bf16x8 raw = *(const bf16x8*)((const u16*)x + (size_t)srow * DM + k);
#pragma unroll
      for (int j = 0; j < 8; ++j) xv[j] = bf2f((u16)raw[j]);
    }
    bf16x8 a;
#pragma unroll
    for (int j = 0; j < 8; ++j)
      a[j] = (short)f2bf((xv[j] - mu) * rs * g_s[k + j] + b_s[k + j]);
#pragma unroll
    for (int c = 0; c < 4; ++c) {
      bf16x8 bf = *(const bf16x8*)(W + (size_t)(n0 + c * 16 + lm) * DM + k);
      acc[c] = MFMA(a, bf, acc[c]);
    }
  }
  u16* out = xz + (size_t)dir * ROWS * NXZ;
#pragma unroll
  for (int c = 0; c < 4; ++c)
#pragma unroll
    for (int r = 0; r < 4; ++r)
      out[(size_t)(m0 + quad * 4 + r) * NXZ + n0 + c * 16 + lm] = f2bf(acc[c][r]);
}

// ---------------------------------------------------------------------------
// K3: depthwise causal conv (width 4) + silu, 8 channels/thread (bf16x8).
// ---------------------------------------------------------------------------
__global__ __launch_bounds__(256) void conv_kernel(
    const void* __restrict__ x,
    const u16* __restrict__ xz, const void* __restrict__ f_cw,
    const void* __restrict__ f_cb, const void* __restrict__ b_cw,
    const void* __restrict__ b_cb, u16* __restrict__ xc) {
  int f32 = detect_f32(x);
  int idx = blockIdx.x * 256 + threadIdx.x;   // [0, 2*2048*64)
  int g   = idx & 63;
  int row = (idx >> 6) & (ROWS - 1);
  int dir = idx >> 17;
  int tpos = row & 1023;
  int d0 = g * 8;
  const void* cw = dir ? b_cw : f_cw;
  const void* cb = dir ? b_cb : f_cb;
  const u16* xi = xz + (size_t)dir * ROWS * NXZ;
  float s[8];
#pragma unroll
  for (int e = 0; e < 8; ++e) s[e] = ldx(cb, d0 + e, f32);
#pragma unroll
  for (int k = 0; k < 4; ++k) {
    int tt = tpos - 3 + k;
    if (tt >= 0) {
      bf16x8 xv = *(const bf16x8*)(xi + (size_t)(row + k - 3) * NXZ + d0);
#pragma unroll
      for (int e = 0; e < 8; ++e)
        s[e] += ldx(cw, (d0 + e) * 4 + k, f32) * bf2f((u16)xv[e]);
    }
  }
  bf16x8 ov;
#pragma unroll
  for (int e = 0; e < 8; ++e) {
    float sl = s[e] / (1.0f + __expf(-s[e]));
    ov[e] = (short)f2bf(sl);
  }
  *(bf16x8*)(xc + ((size_t)dir * ROWS + row) * DI + d0) = ov;
}

// ---------------------------------------------------------------------------
// K4: x-projection (MFMA) with packed outputs: tile 0 -> dtin[4096][16],
// tiles 1..8 -> BC[4096][128] (B cols 0..63, C cols 64..127).
// grid (64, 9), block 256 (4 waves along m). Wave: 16m x 16n, K=512.
// ---------------------------------------------------------------------------
__global__ __launch_bounds__(256) void xproj_kernel(
    const u16* __restrict__ xc, const u16* __restrict__ wb,
    float* __restrict__ dtin, float* __restrict__ BC) {
  int wave = threadIdx.x >> 6, lane = threadIdx.x & 63;
  int m0 = blockIdx.x * 64 + wave * 16;          // [0, 4096)
  int n0 = blockIdx.y * 16;
  int lm = lane & 15, quad = lane >> 4;
  const short* W = (const short*)(wb + ((m0 & 2048) ? WB_XPB : WB_XPF));
  const short* X = (const short*)xc;
  f32x4 acc = {};
  for (int k0 = 0; k0 < DI; k0 += 32) {
    bf16x8 a  = *(const bf16x8*)(X + (size_t)(m0 + lm) * DI + k0 + quad * 8);
    bf16x8 bf = *(const bf16x8*)(W + (size_t)(n0 + lm) * DI + k0 + quad * 8);
    acc = MFMA(a, bf, acc);
  }
  if (blockIdx.y == 0) {
#pragma unroll
    for (int r = 0; r < 4; ++r)
      dtin[(size_t)(m0 + quad * 4 + r) * 16 + lm] = acc[r];
  } else {
    int col = n0 - 16 + lm;
#pragma unroll
    for (int r = 0; r < 4; ++r)
      BC[(size_t)(m0 + quad * 4 + r) * 128 + col] = acc[r];
  }
}

// ---------------------------------------------------------------------------
// K5: scan_prep. dt = softplus(dtin @ dt_w.T + dt_b); write transposed
// dtT / dxT = dt*xc (bf16, [dirb][d][t]). grid 512, block 256.
// ---------------------------------------------------------------------------
__global__ __launch_bounds__(256) void scan_prep(
    const void* __restrict__ x,
    const float* __restrict__ dtin, const u16* __restrict__ xc,
    const u16* __restrict__ wb, const void* __restrict__ f_db,
    const void* __restrict__ b_db, u16* __restrict__ dtT,
    u16* __restrict__ dxT) {
  int f32 = detect_f32(x);
  int blk = blockIdx.x, tid = threadIdx.x;
  int dirb = blk >> 7, t0 = (blk & 127) * 8;
  int dir = dirb >> 1;
  __shared__ float dblr[8][16];
  if (tid < 128)
    ((float*)dblr)[tid] = dtin[(size_t)(dirb * 1024 + t0) * 16 + tid];
  __syncthreads();
  const u16* dwbase = wb + (dir ? WB_DWB : WB_DWF);
  const void* db = dir ? b_db : f_db;
#pragma unroll
  for (int half = 0; half < 2; ++half) {
    int n = tid + half * 256;
    bf16x8 w0 = *(const bf16x8*)(dwbase + n * 16);
    bf16x8 w1 = *(const bf16x8*)(dwbase + n * 16 + 8);
    float bias = ldx(db, n, f32);
    bf16x8 v1, v2;
#pragma unroll
    for (int t = 0; t < 8; ++t) {
      float acc = bias;
#pragma unroll
      for (int k = 0; k < 8; ++k) acc += dblr[t][k] * bf2f((u16)w0[k]);
#pragma unroll
      for (int k = 0; k < 8; ++k) acc += dblr[t][8 + k] * bf2f((u16)w1[k]);
      float sp = (acc > 20.0f) ? acc : log1pf(__expf(acc));
      float xcv = bf2f(xc[(size_t)(dirb * 1024 + t0 + t) * DI + n]);
      v1[t] = (short)f2bf(sp);
      v2[t] = (short)f2bf(sp * xcv);
    }
    size_t ob = (size_t)(dirb * 512 + n) * 1024 + t0;
    *(bf16x8*)(dtT + ob) = v1;
    *(bf16x8*)(dxT + ob) = v2;
  }
}

// ---------------------------------------------------------------------------
// K6a: scan pass 1 — per-chunk (S = sum dt, b = h_end) for chunks 0..30.
// Wave = (dirb, d-block of 8); lane = (grp = d_sub, sub = n-block);
// each lane owns 8 states of one channel, all in registers.
// grid (64, 31), block 256.
// ---------------------------------------------------------------------------
__global__ __launch_bounds__(256) void scan_pass1(
    const void* __restrict__ x,
    const u16* __restrict__ dtT, const u16* __restrict__ dxT,
    const float* __restrict__ BC,
    const void* __restrict__ f_Al, const void* __restrict__ b_Al,
    float* __restrict__ Sch, u16* __restrict__ Bch) {
  int f32 = detect_f32(x);
  int flat = blockIdx.x * 4 + (threadIdx.x >> 6);   // [0,256) = dirb*64+dblk
  int flatu = __builtin_amdgcn_readfirstlane(flat);
  int dirb = flatu >> 6, dblk = flatu & 63;
  int dir = dirb >> 1;
  int c = blockIdx.y;                                // 0..30
  int lane = threadIdx.x & 63;
  int grp = lane >> 3, sub = lane & 7;
  int d = dblk * 8 + grp;
  const void* Al = dir ? b_Al : f_Al;
  float A2[8];
#pragma unroll
  for (int i = 0; i < 8; ++i)
    A2[i] = -__expf(ldx(Al, d * DS + sub * 8 + i, f32)) * LOG2E;
  size_t tb = (size_t)(dirb * 512 + d) * 1024;
  float h[8] = {};
  float S = 0.0f;
  int tbeg = c * CHL;
  for (int t0 = tbeg; t0 < tbeg + CHL; t0 += 8) {
    bf16x8 dt8 = *(const bf16x8*)(dtT + tb + t0);
    bf16x8 dx8 = *(const bf16x8*)(dxT + tb + t0);
    const float* bp = BC + (size_t)(dirb * 1024 + t0) * 128 + sub * 8;
#pragma unroll
    for (int j = 0; j < 8; ++j) {
      float dtv = bf2f((u16)dt8[j]);
      float dxv = bf2f((u16)dx8[j]);
      f32x4 B0 = *(const f32x4*)(bp + j * 128);
      f32x4 B1 = *(const f32x4*)(bp + j * 128 + 4);
      S += dtv;
#pragma unroll
      for (int i = 0; i < 4; ++i) {
        h[i]     = EXP2(dtv * A2[i])     * h[i]     + dxv * B0[i];
        h[i + 4] = EXP2(dtv * A2[i + 4]) * h[i + 4] + dxv * B1[i];
      }
    }
  }
  size_t o = ((size_t)(dirb * 512 + d) * (NCH - 1) + c) * 64 + sub * 8;
  bf16x8 hb;
#pragma unroll
  for (int i = 0; i < 8; ++i) hb[i] = (short)f2bf(h[i]);
  *(bf16x8*)(Bch + o) = hb;
  if (sub == 0) Sch[(size_t)(dirb * 512 + d) * (NCH - 1) + c] = S;
}

// ---------------------------------------------------------------------------
// K6fix: compose chunk summaries in place (f32 internal, bf16 stored).
// Thread = (dirb, d, n); serial over 31 chunks: h = exp2(A2*S)*h + b.
// grid 512, block 256.
// ---------------------------------------------------------------------------
__global__ __launch_bounds__(256) void scan_fix(
    const void* __restrict__ x,
    const void* __restrict__ f_Al, const void* __restrict__ b_Al,
    const float* __restrict__ Sch, u16* __restrict__ Bch) {
  int f32 = detect_f32(x);
  int flat = blockIdx.x * 256 + threadIdx.x;   // [0, 131072)
  int n = flat & 63, dn = flat >> 6;           // dn = dirb*512 + d
  int d = dn & 511, dir = dn >> 10;
  float A2 = -__expf(ldx(dir ? b_Al : f_Al, d * DS + n, f32)) * LOG2E;
  float h = 0.0f;
  for (int cc = 0; cc < NCH - 1; ++cc) {
    float S = Sch[(size_t)dn * (NCH - 1) + cc];
    size_t o = ((size_t)dn * (NCH - 1) + cc) * 64 + n;
    h = EXP2(A2 * S) * h + bf2f(Bch[o]);
    Bch[o] = f2bf(h);
  }
}

// ---------------------------------------------------------------------------
// K6b: scan pass 2 — 32 chunks of 32 in parallel (8192 waves = 8/SIMD);
// lane owns 8 states of one channel; in-register dot + 3 shuffles.
// grid (64, 32), block 256.
// ---------------------------------------------------------------------------
__global__ __launch_bounds__(256) void scan_pass2(
    const void* __restrict__ x,
    const u16* __restrict__ dtT, const u16* __restrict__ dxT,
    const float* __restrict__ BC,
    const u16* __restrict__ xc, const u16* __restrict__ xz,
    const void* __restrict__ f_Al, const void* __restrict__ f_Dp,
    const void* __restrict__ b_Al, const void* __restrict__ b_Dp,
    const u16* __restrict__ Bch, u16* __restrict__ y) {
  int f32 = detect_f32(x);
  int flat = blockIdx.x * 4 + (threadIdx.x >> 6);   // [0,256) = dirb*64+dblk
  int flatu = __builtin_amdgcn_readfirstlane(flat);
  int dirb = flatu >> 6, dblk = flatu & 63;
  int dir = dirb >> 1;
  int c = blockIdx.y;                                // 0..31
  int lane = threadIdx.x & 63;
  int grp = lane >> 3, sub = lane & 7;
  int d = dblk * 8 + grp;
  const void* Al = dir ? b_Al : f_Al;
  float A2[8];
#pragma unroll
  for (int i = 0; i < 8; ++i)
    A2[i] = -__expf(ldx(Al, d * DS + sub * 8 + i, f32)) * LOG2E;
  float Dpd = ldx(dir ? b_Dp : f_Dp, d, f32);
  size_t tb = (size_t)(dirb * 512 + d) * 1024;
  float h[8];
  if (c == 0) {
#pragma unroll
    for (int i = 0; i < 8; ++i) h[i] = 0.0f;
  } else {
    size_t o = ((size_t)(dirb * 512 + d) * (NCH - 1) + (c - 1)) * 64 + sub * 8;
    bf16x8 hb = *(const bf16x8*)(Bch + o);
#pragma unroll
    for (int i = 0; i < 8; ++i) h[i] = bf2f((u16)hb[i]);
  }
  int tbeg = c * CHL;
  for (int t0 = tbeg; t0 < tbeg + CHL; t0 += 8) {
    bf16x8 dt8 = *(const bf16x8*)(dtT + tb + t0);
    bf16x8 dx8 = *(const bf16x8*)(dxT + tb + t0);
    const float* bp = BC + (size_t)(dirb * 1024 + t0) * 128 + sub * 8;
#pragma unroll
    for (int j = 0; j < 8; ++j) {
      float dtv = bf2f((u16)dt8[j]);
      float dxv = bf2f((u16)dx8[j]);
      f32x4 B0 = *(const f32x4*)(bp + j * 128);
      f32x4 B1 = *(const f32x4*)(bp + j * 128 + 4);
      f32x4 C0 = *(const f32x4*)(bp + j * 128 + 64);
      f32x4 C1 = *(const f32x4*)(bp + j * 128 + 68);
      float p = 0.0f;
#pragma unroll
      for (int i = 0; i < 4; ++i) {
        h[i]     = EXP2(dtv * A2[i])     * h[i]     + dxv * B0[i];
        p += h[i] * C0[i];
        h[i + 4] = EXP2(dtv * A2[i + 4]) * h[i + 4] + dxv * B1[i];
        p += h[i + 4] * C1[i];
      }
      // sum over the 8 lanes sharing this channel (64 states total)
      p += __shfl_xor(p, 1);
      p += __shfl_xor(p, 2);
      p += __shfl_xor(p, 4);
      if (sub == 0) {
        int t = t0 + j;
        size_t row = (size_t)(dirb * 1024 + t);
        float xcv = bf2f(xc[row * DI + d]);
        float zv  = bf2f(xz[row * NXZ + DI + d]);
        float yv = (p + xcv * Dpd) * (zv / (1.0f + __expf(-zv)));
        y[row * DI + d] = f2bf(yv);
      }
    }
  }
}

// ---------------------------------------------------------------------------
// K7: out-projection + LN2 + final GEMM + GELU, 512-thread blocks.
// Waves 0-3 fwd GEMM, waves 4-7 bwd GEMM (16m x 64n, K=512 each); bwd accs
// combined via LDS; waves 0-3 LN2 -> bf16 x2 tile in LDS; all 8 waves do the
// final GEMM (32-col strips, K=256 from LDS) + exact GELU. grid 128.
// ---------------------------------------------------------------------------
__global__ __launch_bounds__(512) void outproj_ln2_final_kernel(
    const void* __restrict__ x,
    const u16* __restrict__ y, const u16* __restrict__ wb,
    const void* __restrict__ g, const void* __restrict__ bta,
    const void* __restrict__ b2, void* __restrict__ out) {
  int f32 = detect_f32(x);
  int tid = threadIdx.x;
  int wave = tid >> 6, lane = tid & 63;
  int dirg = wave >> 2, wsub = wave & 3;
  int m0 = blockIdx.x * 16;
  int n0 = wsub * 64;
  int lm = lane & 15, quad = lane >> 4;
  const short* Y = (const short*)y;
  int m  = m0 + lm;
  int bb = m >> 10, t = m & 1023;
  int srow = dirg ? (ROWS + bb * 1024 + (1023 - t)) : m;
  const short* W = (const short*)(wb + (dirg ? WB_OWB : WB_OWF));
  f32x4 acc[4] = {};
  for (int k0 = 0; k0 < DI; k0 += 32) {
    bf16x8 a = *(const bf16x8*)(Y + (size_t)srow * DI + k0 + quad * 8);
#pragma unroll
    for (int c = 0; c < 4; ++c) {
      bf16x8 bf = *(const bf16x8*)(W + (size_t)(n0 + c * 16 + lm) * DI + k0 + quad * 8);
      acc[c] = MFMA(a, bf, acc[c]);
    }
  }
  __shared__ float accB[16][260];          // +4 pad: <=2-way conflicts (free)
  __shared__ float S1[16][4], S2[16][4];
  __shared__ u16 x2s[16][DM + 8];
  if (dirg == 1)
#pragma unroll
    for (int c = 0; c < 4; ++c)
#pragma unroll
      for (int r = 0; r < 4; ++r)
        accB[quad * 4 + r][n0 + c * 16 + lm] = acc[c][r];
  __syncthreads();
  if (dirg == 0) {
#pragma unroll
    for (int c = 0; c < 4; ++c)
#pragma unroll
      for (int r = 0; r < 4; ++r)
        acc[c][r] += accB[quad * 4 + r][n0 + c * 16 + lm];
    // ---- LN2 stats over the wave's 64-col strip ----
    float ps[4], pq[4];
#pragma unroll
    for (int r = 0; r < 4; ++r) {
      ps[r] = acc[0][r] + acc[1][r] + acc[2][r] + acc[3][r];
      pq[r] = acc[0][r] * acc[0][r] + acc[1][r] * acc[1][r] +
              acc[2][r] * acc[2][r] + acc[3][r] * acc[3][r];
    }
#pragma unroll
    for (int off = 1; off < 16; off <<= 1)
#pragma unroll
      for (int r = 0; r < 4; ++r) {
        ps[r] += __shfl_xor(ps[r], off);
        pq[r] += __shfl_xor(pq[r], off);
      }
    if (lm == 0)
#pragma unroll
      for (int r = 0; r < 4; ++r) {
        S1[quad * 4 + r][wsub] = ps[r];
        S2[quad * 4 + r][wsub] = pq[r];
      }
  }
  __syncthreads();
  if (dirg == 0) {
#pragma unroll
    for (int r = 0; r < 4; ++r) {
      int row = quad * 4 + r;
      float s1 = S1[row][0] + S1[row][1] + S1[row][2] + S1[row][3];
      float s2 = S2[row][0] + S2[row][1] + S2[row][2] + S2[row][3];
      float m_ = s1 * (1.0f / DM);
      float v_ = s2 * (1.0f / DM) - m_ * m_;
      float rs = rsqrtf(v_ + 1e-5f);
#pragma unroll
      for (int c = 0; c < 4; ++c) {
        int col = n0 + c * 16 + lm;
        float val = (acc[c][r] - m_) * rs * ldx(g, col, f32) + ldx(bta, col, f32);
        x2s[row][col] = f2bf(val);
      }
    }
  }
  __syncthreads();
  // ---- final GEMM: 8 waves x 32-col strips, K=256 from LDS ----
  const short* W2 = (const short*)(wb + WB_W2);
  int n0f = wave * 32;
  f32x4 facc[2] = {};
  for (int k0 = 0; k0 < DM; k0 += 32) {
    int k = k0 + quad * 8;
    bf16x8 a = *(const bf16x8*)&x2s[lm][k];
#pragma unroll
    for (int c = 0; c < 2; ++c) {
      bf16x8 bf = *(const bf16x8*)(W2 + (size_t)(n0f + c * 16 + lm) * DM + k);
      facc[c] = MFMA(a, bf, facc[c]);
    }
  }
#pragma unroll
  for (int c = 0; c < 2; ++c)
#pragma unroll
    for (int r = 0; r < 4; ++r) {
      int col = n0f + c * 16 + lm;
      float v = facc[c][r] + ldx(b2, col, f32);
      float gl = 0.5f * v * (1.0f + erff(v * 0.70710678118654752f));
      size_t o = (size_t)(m0 + quad * 4 + r) * DM + col;
      if (f32) ((float*)out)[o] = gl;
      else     ((u16*)out)[o]   = f2bf(gl);
    }
}

// ---------------------------------------------------------------------------
extern "C" void kernel_launch(void* const* d_in, const int* in_sizes, int n_in,
                              void* d_out, int out_size, void* d_ws, size_t ws_size,
                              hipStream_t stream) {
  const void* x        = d_in[0];
  const void* f_in_w   = d_in[1];
  const void* f_conv_w = d_in[2];
  const void* f_conv_b = d_in[3];
  const void* f_xproj  = d_in[4];
  const void* f_dt_w   = d_in[5];
  const void* f_dt_b   = d_in[6];
  const void* f_A_log  = d_in[7];
  const void* f_Dp     = d_in[8];
  const void* f_out_w  = d_in[9];
  const void* b_in_w   = d_in[10];
  const void* b_conv_w = d_in[11];
  const void* b_conv_b = d_in[12];
  const void* b_xproj  = d_in[13];
  const void* b_dt_w   = d_in[14];
  const void* b_dt_b   = d_in[15];
  const void* b_A_log  = d_in[16];
  const void* b_Dp     = d_in[17];
  const void* b_out_w  = d_in[18];
  const void* ln1_g    = d_in[19];
  const void* ln1_b    = d_in[20];
  const void* ln2_g    = d_in[21];
  const void* ln2_b    = d_in[22];
  const void* w2       = d_in[23];
  const void* b2       = d_in[24];

  char* ws = (char*)d_ws;
  u16*   xz   = (u16*)(ws + XZ_OFF);
  u16*   xc   = (u16*)(ws + XC_OFF);
  float* dtin = (float*)(ws + DTIN_OFF);
  float* BC   = (float*)(ws + BC_OFF);
  u16*   dtT  = (u16*)(ws + DTT_OFF);
  u16*   dxT  = (u16*)(ws + DXT_OFF);
  u16*   y    = (u16*)(ws + Y_OFF);
  float* Sch  = (float*)(ws + SCH_OFF);
  u16*   Bch  = (u16*)(ws + BCH_OFF);
  u16*   wb   = (u16*)(ws + WB_OFF);

  convert_kernel<<<(WB_TOT + 255) / 256, 256, 0, stream>>>(
      x, f_in_w, b_in_w, f_xproj, b_xproj, f_out_w, b_out_w, w2, f_dt_w,
      b_dt_w, wb);
  inproj_ln1_kernel<<<dim3(ROWS / 16, 4, 2), 256, 0, stream>>>(
      x, ln1_g, ln1_b, wb, xz);
  conv_kernel<<<(2 * ROWS * 64) / 256, 256, 0, stream>>>(
      x, xz, f_conv_w, f_conv_b, b_conv_w, b_conv_b, xc);
  xproj_kernel<<<dim3(64, 9), 256, 0, stream>>>(xc, wb, dtin, BC);
  scan_prep<<<512, 256, 0, stream>>>(
      x, dtin, xc, wb, f_dt_b, b_dt_b, dtT, dxT);
  scan_pass1<<<dim3(64, NCH - 1), 256, 0, stream>>>(
      x, dtT, dxT, BC, f_A_log, b_A_log, Sch, Bch);
  scan_fix<<<512, 256, 0, stream>>>(x, f_A_log, b_A_log, Sch, Bch);
  scan_pass2<<<dim3(64, NCH), 256, 0, stream>>>(
      x, dtT, dxT, BC, xc, xz, f_A_log, f_Dp, b_A_log, b_Dp, Bch, y);
  outproj_ln2_final_kernel<<<128, 512, 0, stream>>>(
      x, y, wb, ln2_g, ln2_b, b2, d_out);
}

// Round 16
// 296.594 us; speedup vs baseline: 1.0511x; 1.0511x over previous
//
#include <hip/hip_runtime.h>

// ---------------------------------------------------------------------------
// BiMambaEncoderBlock on MI355X (gfx950). fp32 accumulate, bf16 intermediates.
// B=2, S=1024, D_MODEL=256, D_INNER=512, D_STATE=64, DT_RANK=16, D_CONV=4.
// Round 16: scan reverted to round-14 config (16 chunks of 64, f32 Bch —
// r15's 32x32 split raised per-block overhead with no latency win). Out-
// projection split: GEMM phase on grid (128,2) (dir = block axis -> 256
// blocks, all CUs busy; was 128 blocks = half idle), f32 partials in the
// retired xz region; ln2_final kernel sums + LN2 + final GEMM + GELU.
// ---------------------------------------------------------------------------

typedef unsigned short u16;
typedef short bf16x8 __attribute__((ext_vector_type(8)));   // 8 bf16 = 4 VGPRs
typedef float f32x4  __attribute__((ext_vector_type(4)));

#define MFMA(a, b, c) __builtin_amdgcn_mfma_f32_16x16x32_bf16((a), (b), (c), 0, 0, 0)
#if __has_builtin(__builtin_amdgcn_exp2f)
#define EXP2(x) __builtin_amdgcn_exp2f(x)
#else
#define EXP2(x) exp2f(x)
#endif
static constexpr float LOG2E = 1.44269504088896340736f;

static constexpr int ROWS = 2048;   // B*S
static constexpr int DM   = 256;    // d_model
static constexpr int DI   = 512;    // d_inner
static constexpr int NXZ  = 1024;   // 2*d_inner
static constexpr int DS   = 64;     // d_state
static constexpr int NCH  = 16;     // scan chunks
static constexpr int CHL  = 64;     // chunk length

__device__ __forceinline__ float bf2f(u16 u) {
  union { unsigned u32; float f; } v; v.u32 = ((unsigned)u) << 16; return v.f;
}
__device__ __forceinline__ u16 f2bf(float f) {
  union { float f; unsigned u; } v; v.f = f;
  unsigned r = v.u + 0x7FFFu + ((v.u >> 16) & 1u);   // RNE (finite inputs)
  return (u16)(r >> 16);
}
__device__ __forceinline__ float ldx(const void* p, size_t i, int f32) {
  return f32 ? ((const float*)p)[i] : bf2f(((const u16*)p)[i]);
}
// wave-uniform dtype detect: even u16s of f32 data are uniform-random bf16
// patterns (P[all 64 within +-1024] ~ 4e-18); bf16 N(0,1) data always passes.
__device__ __forceinline__ int detect_f32(const void* xp) {
  const u16* p = (const u16*)xp;
  int lane = threadIdx.x & 63;
  float v = bf2f(p[lane * 2]);
  int bad = !(v > -1024.0f && v < 1024.0f);
  return (__ballot(bad) != 0ull) ? 1 : 0;
}

// ---- workspace layout (bytes) ----
static constexpr size_t XZ_OFF   = 0;          // bf16 [2][2048][1024]; later: f32 op[2][2048][256]
static constexpr size_t XC_OFF   = 8388608;    // bf16 [4096][512]  (row=dirb*1024+t)
static constexpr size_t DTIN_OFF = 12582912;   // f32  [4096][16]   dt-proj inputs
static constexpr size_t BC_OFF   = 12845056;   // f32  [4096][128]  B(0:64) C(64:128)
static constexpr size_t DTT_OFF  = 14942208;   // bf16 [4][512][1024]  dt  (dirb,d,t)
static constexpr size_t DXT_OFF  = 19136512;   // bf16 [4][512][1024]  dt*xc
static constexpr size_t Y_OFF    = 23330816;   // bf16 [4096][512]
static constexpr size_t SCH_OFF  = 27525120;   // f32  [2048][15]      sum(dt) per chunk
static constexpr size_t BCH_OFF  = 27648000;   // f32  [2048][15][64]  chunk h_end -> h_in
static constexpr size_t WB_OFF   = 35512320;   // bf16 weights
// converted-weight region (element offsets within WB):
static constexpr int WB_IWF = 0;        // f_in_w  [1024][256]
static constexpr int WB_IWB = 262144;   // b_in_w  [1024][256]
static constexpr int WB_XPF = 524288;   // f_xproj [144][512]
static constexpr int WB_XPB = 598016;   // b_xproj [144][512]
static constexpr int WB_OWF = 671744;   // f_out_w [256][512]
static constexpr int WB_OWB = 802816;   // b_out_w [256][512]
static constexpr int WB_W2  = 933888;   // w2      [256][256]
static constexpr int WB_DWF = 999424;   // f_dt_w  [512][16]
static constexpr int WB_DWB = 1007616;  // b_dt_w  [512][16]
static constexpr int WB_TOT = 1015808;
// total ws ≈ 36.5 MiB (< 39.2 MiB proven in round 7)

// ---------------------------------------------------------------------------
// K0b: convert all GEMM weights to bf16 into ws (identity if already bf16).
// ---------------------------------------------------------------------------
__global__ __launch_bounds__(256) void convert_kernel(
    const void* __restrict__ x,
    const void* __restrict__ f_iw, const void* __restrict__ b_iw,
    const void* __restrict__ f_xp, const void* __restrict__ b_xp,
    const void* __restrict__ f_ow, const void* __restrict__ b_ow,
    const void* __restrict__ w2,   const void* __restrict__ f_dw,
    const void* __restrict__ b_dw, u16* __restrict__ wb) {
  int f32 = detect_f32(x);
  int i = blockIdx.x * 256 + threadIdx.x;
  if (i >= WB_TOT) return;
  const void* src; int off;
  if      (i < WB_IWB) { src = f_iw; off = i - WB_IWF; }
  else if (i < WB_XPF) { src = b_iw; off = i - WB_IWB; }
  else if (i < WB_XPB) { src = f_xp; off = i - WB_XPF; }
  else if (i < WB_OWF) { src = b_xp; off = i - WB_XPB; }
  else if (i < WB_OWB) { src = f_ow; off = i - WB_OWF; }
  else if (i < WB_W2)  { src = b_ow; off = i - WB_OWB; }
  else if (i < WB_DWF) { src = w2;   off = i - WB_W2;  }
  else if (i < WB_DWB) { src = f_dw; off = i - WB_DWF; }
  else                 { src = b_dw; off = i - WB_DWB; }
  wb[i] = f2bf(ldx(src, (size_t)off, f32));
}

// ---------------------------------------------------------------------------
// K2: fused LayerNorm1 + in-projection (MFMA).
// xz[dir][m][:] = LN(x[srow(m)]) @ in_w.T  (K=256).
// grid (128, 4, 2), block 256. Wave: 16m x 64n.
// ---------------------------------------------------------------------------
__global__ __launch_bounds__(256) void inproj_ln1_kernel(
    const void* __restrict__ x, const void* __restrict__ g,
    const void* __restrict__ b, const u16* __restrict__ wb,
    u16* __restrict__ xz) {
  int f32 = detect_f32(x);
  int dir  = blockIdx.z;
  int tid  = threadIdx.x;
  int wave = tid >> 6, lane = tid & 63;
  int m0 = blockIdx.x * 16;
  int n0 = blockIdx.y * 256 + wave * 64;
  int bb0 = m0 >> 10;
  __shared__ float S1[16][17], S2[16][17];
  __shared__ float mu_s[16], rs_s[16];
  __shared__ float g_s[DM], b_s[DM];
  // stage 1: LN stats for the block's 16 source rows
  {
    int r = tid & 15, ch = tid >> 4;           // row, 16-col chunk
    int mr = m0 + r, tpos = mr & 1023;
    int srow_r = dir ? (bb0 * 1024 + (1023 - tpos)) : mr;
    float s = 0.0f, s2 = 0.0f;
#pragma unroll
    for (int i = 0; i < 16; ++i) {
      float v = ldx(x, (size_t)srow_r * DM + ch * 16 + i, f32);
      s += v; s2 += v * v;
    }
    S1[r][ch] = s; S2[r][ch] = s2;
    g_s[tid] = ldx(g, tid, f32);
    b_s[tid] = ldx(b, tid, f32);
  }
  __syncthreads();
  if (tid < 16) {
    float a = 0.0f, q = 0.0f;
#pragma unroll
    for (int c = 0; c < 16; ++c) { a += S1[tid][c]; q += S2[tid][c]; }
    float m_ = a * (1.0f / DM);
    float v_ = q * (1.0f / DM) - m_ * m_;
    mu_s[tid] = m_;
    rs_s[tid] = rsqrtf(v_ + 1e-5f);
  }
  __syncthreads();
  // stage 2: MFMA with normalized A-fragment
  int lm = lane & 15, quad = lane >> 4;
  const short* W = (const short*)(wb + (dir ? WB_IWB : WB_IWF));
  int m = m0 + lm;
  int tpos = m & 1023;
  int srow = dir ? (bb0 * 1024 + (1023 - tpos)) : m;
  float mu = mu_s[lm], rs = rs_s[lm];
  f32x4 acc[4] = {};
  for (int k0 = 0; k0 < DM; k0 += 32) {
    int k = k0 + quad * 8;
    float xv[8];
    if (f32) {
      f32x4 x0 = *(const f32x4*)((const float*)x + (size_t)srow * DM + k);
      f32x4 x1 = *(const f32x4*)((const float*)x + (size_t)srow * DM + k + 4);
#pragma unroll
      for (int j = 0; j < 4; ++j) { xv[j] = x0[j]; xv[4 + j] = x1[j]; }
    } else {
      bf16x8 raw = *(const bf16x8*)((const u16*)x + (size_t)srow * DM + k);
#pragma unroll
      for (int j = 0; j < 8; ++j) xv[j] = bf2f((u16)raw[j]);
    }
    bf16x8 a;
#pragma unroll
    for (int j = 0; j < 8; ++j)
      a[j] = (short)f2bf((xv[j] - mu) * rs * g_s[k + j] + b_s[k + j]);
#pragma unroll
    for (int c = 0; c < 4; ++c) {
      bf16x8 bf = *(const bf16x8*)(W + (size_t)(n0 + c * 16 + lm) * DM + k);
      acc[c] = MFMA(a, bf, acc[c]);
    }
  }
  u16* out = xz + (size_t)dir * ROWS * NXZ;
#pragma unroll
  for (int c = 0; c < 4; ++c)
#pragma unroll
    for (int r = 0; r < 4; ++r)
      out[(size_t)(m0 + quad * 4 + r) * NXZ + n0 + c * 16 + lm] = f2bf(acc[c][r]);
}

// ---------------------------------------------------------------------------
// K3: depthwise causal conv (width 4) + silu, 8 channels/thread (bf16x8).
// ---------------------------------------------------------------------------
__global__ __launch_bounds__(256) void conv_kernel(
    const void* __restrict__ x,
    const u16* __restrict__ xz, const void* __restrict__ f_cw,
    const void* __restrict__ f_cb, const void* __restrict__ b_cw,
    const void* __restrict__ b_cb, u16* __restrict__ xc) {
  int f32 = detect_f32(x);
  int idx = blockIdx.x * 256 + threadIdx.x;   // [0, 2*2048*64)
  int g   = idx & 63;
  int row = (idx >> 6) & (ROWS - 1);
  int dir = idx >> 17;
  int tpos = row & 1023;
  int d0 = g * 8;
  const void* cw = dir ? b_cw : f_cw;
  const void* cb = dir ? b_cb : f_cb;
  const u16* xi = xz + (size_t)dir * ROWS * NXZ;
  float s[8];
#pragma unroll
  for (int e = 0; e < 8; ++e) s[e] = ldx(cb, d0 + e, f32);
#pragma unroll
  for (int k = 0; k < 4; ++k) {
    int tt = tpos - 3 + k;
    if (tt >= 0) {
      bf16x8 xv = *(const bf16x8*)(xi + (size_t)(row + k - 3) * NXZ + d0);
#pragma unroll
      for (int e = 0; e < 8; ++e)
        s[e] += ldx(cw, (d0 + e) * 4 + k, f32) * bf2f((u16)xv[e]);
    }
  }
  bf16x8 ov;
#pragma unroll
  for (int e = 0; e < 8; ++e) {
    float sl = s[e] / (1.0f + __expf(-s[e]));
    ov[e] = (short)f2bf(sl);
  }
  *(bf16x8*)(xc + ((size_t)dir * ROWS + row) * DI + d0) = ov;
}

// ---------------------------------------------------------------------------
// K4: x-projection (MFMA) with packed outputs: tile 0 -> dtin[4096][16],
// tiles 1..8 -> BC[4096][128] (B cols 0..63, C cols 64..127).
// grid (64, 9), block 256 (4 waves along m). Wave: 16m x 16n, K=512.
// ---------------------------------------------------------------------------
__global__ __launch_bounds__(256) void xproj_kernel(
    const u16* __restrict__ xc, const u16* __restrict__ wb,
    float* __restrict__ dtin, float* __restrict__ BC) {
  int wave = threadIdx.x >> 6, lane = threadIdx.x & 63;
  int m0 = blockIdx.x * 64 + wave * 16;          // [0, 4096)
  int n0 = blockIdx.y * 16;
  int lm = lane & 15, quad = lane >> 4;
  const short* W = (const short*)(wb + ((m0 & 2048) ? WB_XPB : WB_XPF));
  const short* X = (const short*)xc;
  f32x4 acc = {};
  for (int k0 = 0; k0 < DI; k0 += 32) {
    bf16x8 a  = *(const bf16x8*)(X + (size_t)(m0 + lm) * DI + k0 + quad * 8);
    bf16x8 bf = *(const bf16x8*)(W + (size_t)(n0 + lm) * DI + k0 + quad * 8);
    acc = MFMA(a, bf, acc);
  }
  if (blockIdx.y == 0) {
#pragma unroll
    for (int r = 0; r < 4; ++r)
      dtin[(size_t)(m0 + quad * 4 + r) * 16 + lm] = acc[r];
  } else {
    int col = n0 - 16 + lm;
#pragma unroll
    for (int r = 0; r < 4; ++r)
      BC[(size_t)(m0 + quad * 4 + r) * 128 + col] = acc[r];
  }
}

// ---------------------------------------------------------------------------
// K5: scan_prep. dt = softplus(dtin @ dt_w.T + dt_b); write transposed
// dtT / dxT = dt*xc (bf16, [dirb][d][t]). grid 512, block 256.
// ---------------------------------------------------------------------------
__global__ __launch_bounds__(256) void scan_prep(
    const void* __restrict__ x,
    const float* __restrict__ dtin, const u16* __restrict__ xc,
    const u16* __restrict__ wb, const void* __restrict__ f_db,
    const void* __restrict__ b_db, u16* __restrict__ dtT,
    u16* __restrict__ dxT) {
  int f32 = detect_f32(x);
  int blk = blockIdx.x, tid = threadIdx.x;
  int dirb = blk >> 7, t0 = (blk & 127) * 8;
  int dir = dirb >> 1;
  __shared__ float dblr[8][16];
  if (tid < 128)
    ((float*)dblr)[tid] = dtin[(size_t)(dirb * 1024 + t0) * 16 + tid];
  __syncthreads();
  const u16* dwbase = wb + (dir ? WB_DWB : WB_DWF);
  const void* db = dir ? b_db : f_db;
#pragma unroll
  for (int half = 0; half < 2; ++half) {
    int n = tid + half * 256;
    bf16x8 w0 = *(const bf16x8*)(dwbase + n * 16);
    bf16x8 w1 = *(const bf16x8*)(dwbase + n * 16 + 8);
    float bias = ldx(db, n, f32);
    bf16x8 v1, v2;
#pragma unroll
    for (int t = 0; t < 8; ++t) {
      float acc = bias;
#pragma unroll
      for (int k = 0; k < 8; ++k) acc += dblr[t][k] * bf2f((u16)w0[k]);
#pragma unroll
      for (int k = 0; k < 8; ++k) acc += dblr[t][8 + k] * bf2f((u16)w1[k]);
      float sp = (acc > 20.0f) ? acc : log1pf(__expf(acc));
      float xcv = bf2f(xc[(size_t)(dirb * 1024 + t0 + t) * DI + n]);
      v1[t] = (short)f2bf(sp);
      v2[t] = (short)f2bf(sp * xcv);
    }
    size_t ob = (size_t)(dirb * 512 + n) * 1024 + t0;
    *(bf16x8*)(dtT + ob) = v1;
    *(bf16x8*)(dxT + ob) = v2;
  }
}

// ---------------------------------------------------------------------------
// K6a: scan pass 1 — per-chunk (S = sum dt, b = h_end) for chunks 0..14.
// Wave = (dirb, d-block of 8); lane = (grp = d_sub, sub = n-block);
// each lane owns 8 states of one channel, all in registers.
// grid (64, 15), block 256.
// ---------------------------------------------------------------------------
__global__ __launch_bounds__(256) void scan_pass1(
    const void* __restrict__ x,
    const u16* __restrict__ dtT, const u16* __restrict__ dxT,
    const float* __restrict__ BC,
    const void* __restrict__ f_Al, const void* __restrict__ b_Al,
    float* __restrict__ Sch, float* __restrict__ Bch) {
  int f32 = detect_f32(x);
  int flat = blockIdx.x * 4 + (threadIdx.x >> 6);   // [0,256) = dirb*64+dblk
  int flatu = __builtin_amdgcn_readfirstlane(flat);
  int dirb = flatu >> 6, dblk = flatu & 63;
  int dir = dirb >> 1;
  int c = blockIdx.y;                                // 0..14
  int lane = threadIdx.x & 63;
  int grp = lane >> 3, sub = lane & 7;
  int d = dblk * 8 + grp;
  const void* Al = dir ? b_Al : f_Al;
  float A2[8];
#pragma unroll
  for (int i = 0; i < 8; ++i)
    A2[i] = -__expf(ldx(Al, d * DS + sub * 8 + i, f32)) * LOG2E;
  size_t tb = (size_t)(dirb * 512 + d) * 1024;
  float h[8] = {};
  float S = 0.0f;
  int tbeg = c * CHL;
  for (int t0 = tbeg; t0 < tbeg + CHL; t0 += 8) {
    bf16x8 dt8 = *(const bf16x8*)(dtT + tb + t0);
    bf16x8 dx8 = *(const bf16x8*)(dxT + tb + t0);
    const float* bp = BC + (size_t)(dirb * 1024 + t0) * 128 + sub * 8;
#pragma unroll
    for (int j = 0; j < 8; ++j) {
      float dtv = bf2f((u16)dt8[j]);
      float dxv = bf2f((u16)dx8[j]);
      f32x4 B0 = *(const f32x4*)(bp + j * 128);
      f32x4 B1 = *(const f32x4*)(bp + j * 128 + 4);
      S += dtv;
#pragma unroll
      for (int i = 0; i < 4; ++i) {
        h[i]     = EXP2(dtv * A2[i])     * h[i]     + dxv * B0[i];
        h[i + 4] = EXP2(dtv * A2[i + 4]) * h[i + 4] + dxv * B1[i];
      }
    }
  }
  size_t o = ((size_t)(dirb * 512 + d) * (NCH - 1) + c) * 64 + sub * 8;
  f32x4 h0 = {h[0], h[1], h[2], h[3]};
  f32x4 h1 = {h[4], h[5], h[6], h[7]};
  *(f32x4*)(Bch + o) = h0;
  *(f32x4*)(Bch + o + 4) = h1;
  if (sub == 0) Sch[(size_t)(dirb * 512 + d) * (NCH - 1) + c] = S;
}

// ---------------------------------------------------------------------------
// K6fix: compose chunk summaries in place. Thread = (dirb, d, n); serial over
// 15 chunks: h = exp2(A2*S)*h + b; Bch[c] becomes h_in for chunk c+1.
// grid 512, block 256.
// ---------------------------------------------------------------------------
__global__ __launch_bounds__(256) void scan_fix(
    const void* __restrict__ x,
    const void* __restrict__ f_Al, const void* __restrict__ b_Al,
    const float* __restrict__ Sch, float* __restrict__ Bch) {
  int f32 = detect_f32(x);
  int flat = blockIdx.x * 256 + threadIdx.x;   // [0, 131072)
  int n = flat & 63, dn = flat >> 6;           // dn = dirb*512 + d
  int d = dn & 511, dir = dn >> 10;
  float A2 = -__expf(ldx(dir ? b_Al : f_Al, d * DS + n, f32)) * LOG2E;
  float h = 0.0f;
  for (int cc = 0; cc < NCH - 1; ++cc) {
    float S = Sch[(size_t)dn * (NCH - 1) + cc];
    size_t o = ((size_t)dn * (NCH - 1) + cc) * 64 + n;
    h = EXP2(A2 * S) * h + Bch[o];
    Bch[o] = h;
  }
}

// ---------------------------------------------------------------------------
// K6b: scan pass 2 — 16 chunks of 64 in parallel; lane owns 8 states of one
// channel; y = (in-register dot) + 3 shuffles; h_in from Bch[c-1].
// grid (64, 16), block 256.
// ---------------------------------------------------------------------------
__global__ __launch_bounds__(256) void scan_pass2(
    const void* __restrict__ x,
    const u16* __restrict__ dtT, const u16* __restrict__ dxT,
    const float* __restrict__ BC,
    const u16* __restrict__ xc, const u16* __restrict__ xz,
    const void* __restrict__ f_Al, const void* __restrict__ f_Dp,
    const void* __restrict__ b_Al, const void* __restrict__ b_Dp,
    const float* __restrict__ Bch, u16* __restrict__ y) {
  int f32 = detect_f32(x);
  int flat = blockIdx.x * 4 + (threadIdx.x >> 6);   // [0,256) = dirb*64+dblk
  int flatu = __builtin_amdgcn_readfirstlane(flat);
  int dirb = flatu >> 6, dblk = flatu & 63;
  int dir = dirb >> 1;
  int c = blockIdx.y;                                // 0..15
  int lane = threadIdx.x & 63;
  int grp = lane >> 3, sub = lane & 7;
  int d = dblk * 8 + grp;
  const void* Al = dir ? b_Al : f_Al;
  float A2[8];
#pragma unroll
  for (int i = 0; i < 8; ++i)
    A2[i] = -__expf(ldx(Al, d * DS + sub * 8 + i, f32)) * LOG2E;
  float Dpd = ldx(dir ? b_Dp : f_Dp, d, f32);
  size_t tb = (size_t)(dirb * 512 + d) * 1024;
  float h[8];
  if (c == 0) {
#pragma unroll
    for (int i = 0; i < 8; ++i) h[i] = 0.0f;
  } else {
    size_t o = ((size_t)(dirb * 512 + d) * (NCH - 1) + (c - 1)) * 64 + sub * 8;
    f32x4 h0 = *(const f32x4*)(Bch + o);
    f32x4 h1 = *(const f32x4*)(Bch + o + 4);
#pragma unroll
    for (int i = 0; i < 4; ++i) { h[i] = h0[i]; h[i + 4] = h1[i]; }
  }
  int tbeg = c * CHL;
  for (int t0 = tbeg; t0 < tbeg + CHL; t0 += 8) {
    bf16x8 dt8 = *(const bf16x8*)(dtT + tb + t0);
    bf16x8 dx8 = *(const bf16x8*)(dxT + tb + t0);
    const float* bp = BC + (size_t)(dirb * 1024 + t0) * 128 + sub * 8;
#pragma unroll
    for (int j = 0; j < 8; ++j) {
      float dtv = bf2f((u16)dt8[j]);
      float dxv = bf2f((u16)dx8[j]);
      f32x4 B0 = *(const f32x4*)(bp + j * 128);
      f32x4 B1 = *(const f32x4*)(bp + j * 128 + 4);
      f32x4 C0 = *(const f32x4*)(bp + j * 128 + 64);
      f32x4 C1 = *(const f32x4*)(bp + j * 128 + 68);
      float p = 0.0f;
#pragma unroll
      for (int i = 0; i < 4; ++i) {
        h[i]     = EXP2(dtv * A2[i])     * h[i]     + dxv * B0[i];
        p += h[i] * C0[i];
        h[i + 4] = EXP2(dtv * A2[i + 4]) * h[i + 4] + dxv * B1[i];
        p += h[i + 4] * C1[i];
      }
      // sum over the 8 lanes sharing this channel (64 states total)
      p += __shfl_xor(p, 1);
      p += __shfl_xor(p, 2);
      p += __shfl_xor(p, 4);
      if (sub == 0) {
        int t = t0 + j;
        size_t row = (size_t)(dirb * 1024 + t);
        float xcv = bf2f(xc[row * DI + d]);
        float zv  = bf2f(xz[row * NXZ + DI + d]);
        float yv = (p + xcv * Dpd) * (zv / (1.0f + __expf(-zv)));
        y[row * DI + d] = f2bf(yv);
      }
    }
  }
}

// ---------------------------------------------------------------------------
// K7a: out-projection GEMM (one direction per block). grid (128, 2),
// block 256 (4 waves along n, 16m x 64n, K=512). Writes f32 partials into
// the retired xz region: op[dirg][row][col].
// ---------------------------------------------------------------------------
__global__ __launch_bounds__(256) void outproj_kernel(
    const u16* __restrict__ y, const u16* __restrict__ wb,
    float* __restrict__ op) {
  int dirg = blockIdx.y;
  int wave = threadIdx.x >> 6, lane = threadIdx.x & 63;
  int m0 = blockIdx.x * 16;
  int n0 = wave * 64;
  int lm = lane & 15, quad = lane >> 4;
  const short* Y = (const short*)y;
  int m  = m0 + lm;
  int bb = m >> 10, t = m & 1023;
  int srow = dirg ? (ROWS + bb * 1024 + (1023 - t)) : m;
  const short* W = (const short*)(wb + (dirg ? WB_OWB : WB_OWF));
  f32x4 acc[4] = {};
  for (int k0 = 0; k0 < DI; k0 += 32) {
    bf16x8 a = *(const bf16x8*)(Y + (size_t)srow * DI + k0 + quad * 8);
#pragma unroll
    for (int c = 0; c < 4; ++c) {
      bf16x8 bf = *(const bf16x8*)(W + (size_t)(n0 + c * 16 + lm) * DI + k0 + quad * 8);
      acc[c] = MFMA(a, bf, acc[c]);
    }
  }
  float* dst = op + (size_t)dirg * ROWS * DM;
#pragma unroll
  for (int c = 0; c < 4; ++c)
#pragma unroll
    for (int r = 0; r < 4; ++r)
      dst[(size_t)(m0 + quad * 4 + r) * DM + n0 + c * 16 + lm] = acc[c][r];
}

// ---------------------------------------------------------------------------
// K7b: sum partials + LN2 + final GEMM (K=256 from LDS) + exact GELU.
// grid 128, block 256 (4 waves along n, block owns 16 rows).
// ---------------------------------------------------------------------------
__global__ __launch_bounds__(256) void ln2_final_kernel(
    const void* __restrict__ x, const float* __restrict__ op,
    const u16* __restrict__ wb, const void* __restrict__ g,
    const void* __restrict__ bta, const void* __restrict__ b2,
    void* __restrict__ out) {
  int f32 = detect_f32(x);
  int wave = threadIdx.x >> 6, lane = threadIdx.x & 63;
  int m0 = blockIdx.x * 16;
  int n0 = wave * 64;
  int lm = lane & 15, quad = lane >> 4;
  f32x4 acc[4];
#pragma unroll
  for (int c = 0; c < 4; ++c)
#pragma unroll
    for (int r = 0; r < 4; ++r) {
      size_t idx = (size_t)(m0 + quad * 4 + r) * DM + n0 + c * 16 + lm;
      acc[c][r] = op[idx] + op[(size_t)ROWS * DM + idx];
    }
  // ---- LN2 ----
  float ps[4], pq[4];
#pragma unroll
  for (int r = 0; r < 4; ++r) {
    ps[r] = acc[0][r] + acc[1][r] + acc[2][r] + acc[3][r];
    pq[r] = acc[0][r] * acc[0][r] + acc[1][r] * acc[1][r] +
            acc[2][r] * acc[2][r] + acc[3][r] * acc[3][r];
  }
#pragma unroll
  for (int off = 1; off < 16; off <<= 1)
#pragma unroll
    for (int r = 0; r < 4; ++r) {
      ps[r] += __shfl_xor(ps[r], off);
      pq[r] += __shfl_xor(pq[r], off);
    }
  __shared__ float S1[16][4], S2[16][4];
  __shared__ u16 x2s[16][DM + 8];
  if (lm == 0)
#pragma unroll
    for (int r = 0; r < 4; ++r) {
      S1[quad * 4 + r][wave] = ps[r];
      S2[quad * 4 + r][wave] = pq[r];
    }
  __syncthreads();
#pragma unroll
  for (int r = 0; r < 4; ++r) {
    int row = quad * 4 + r;
    float s1 = S1[row][0] + S1[row][1] + S1[row][2] + S1[row][3];
    float s2 = S2[row][0] + S2[row][1] + S2[row][2] + S2[row][3];
    float m_ = s1 * (1.0f / DM);
    float v_ = s2 * (1.0f / DM) - m_ * m_;
    float rs = rsqrtf(v_ + 1e-5f);
#pragma unroll
    for (int c = 0; c < 4; ++c) {
      int col = n0 + c * 16 + lm;
      float val = (acc[c][r] - m_) * rs * ldx(g, col, f32) + ldx(bta, col, f32);
      x2s[row][col] = f2bf(val);
    }
  }
  __syncthreads();
  // ---- final GEMM (K=256 from LDS) + exact GELU ----
  const short* W2 = (const short*)(wb + WB_W2);
  f32x4 facc[4] = {};
  for (int k0 = 0; k0 < DM; k0 += 32) {
    int k = k0 + quad * 8;
    bf16x8 a = *(const bf16x8*)&x2s[lm][k];
#pragma unroll
    for (int c = 0; c < 4; ++c) {
      bf16x8 bf = *(const bf16x8*)(W2 + (size_t)(n0 + c * 16 + lm) * DM + k);
      facc[c] = MFMA(a, bf, facc[c]);
    }
  }
#pragma unroll
  for (int c = 0; c < 4; ++c)
#pragma unroll
    for (int r = 0; r < 4; ++r) {
      int col = n0 + c * 16 + lm;
      float v = facc[c][r] + ldx(b2, col, f32);
      float gl = 0.5f * v * (1.0f + erff(v * 0.70710678118654752f));
      size_t o = (size_t)(m0 + quad * 4 + r) * DM + col;
      if (f32) ((float*)out)[o] = gl;
      else     ((u16*)out)[o]   = f2bf(gl);
    }
}

// ---------------------------------------------------------------------------
extern "C" void kernel_launch(void* const* d_in, const int* in_sizes, int n_in,
                              void* d_out, int out_size, void* d_ws, size_t ws_size,
                              hipStream_t stream) {
  const void* x        = d_in[0];
  const void* f_in_w   = d_in[1];
  const void* f_conv_w = d_in[2];
  const void* f_conv_b = d_in[3];
  const void* f_xproj  = d_in[4];
  const void* f_dt_w   = d_in[5];
  const void* f_dt_b   = d_in[6];
  const void* f_A_log  = d_in[7];
  const void* f_Dp     = d_in[8];
  const void* f_out_w  = d_in[9];
  const void* b_in_w   = d_in[10];
  const void* b_conv_w = d_in[11];
  const void* b_conv_b = d_in[12];
  const void* b_xproj  = d_in[13];
  const void* b_dt_w   = d_in[14];
  const void* b_dt_b   = d_in[15];
  const void* b_A_log  = d_in[16];
  const void* b_Dp     = d_in[17];
  const void* b_out_w  = d_in[18];
  const void* ln1_g    = d_in[19];
  const void* ln1_b    = d_in[20];
  const void* ln2_g    = d_in[21];
  const void* ln2_b    = d_in[22];
  const void* w2       = d_in[23];
  const void* b2       = d_in[24];

  char* ws = (char*)d_ws;
  u16*   xz   = (u16*)(ws + XZ_OFF);
  u16*   xc   = (u16*)(ws + XC_OFF);
  float* dtin = (float*)(ws + DTIN_OFF);
  float* BC   = (float*)(ws + BC_OFF);
  u16*   dtT  = (u16*)(ws + DTT_OFF);
  u16*   dxT  = (u16*)(ws + DXT_OFF);
  u16*   y    = (u16*)(ws + Y_OFF);
  float* Sch  = (float*)(ws + SCH_OFF);
  float* Bch  = (float*)(ws + BCH_OFF);
  u16*   wb   = (u16*)(ws + WB_OFF);
  float* op   = (float*)(ws + XZ_OFF);   // reuses xz after the scan

  convert_kernel<<<(WB_TOT + 255) / 256, 256, 0, stream>>>(
      x, f_in_w, b_in_w, f_xproj, b_xproj, f_out_w, b_out_w, w2, f_dt_w,
      b_dt_w, wb);
  inproj_ln1_kernel<<<dim3(ROWS / 16, 4, 2), 256, 0, stream>>>(
      x, ln1_g, ln1_b, wb, xz);
  conv_kernel<<<(2 * ROWS * 64) / 256, 256, 0, stream>>>(
      x, xz, f_conv_w, f_conv_b, b_conv_w, b_conv_b, xc);
  xproj_kernel<<<dim3(64, 9), 256, 0, stream>>>(xc, wb, dtin, BC);
  scan_prep<<<512, 256, 0, stream>>>(
      x, dtin, xc, wb, f_dt_b, b_dt_b, dtT, dxT);
  scan_pass1<<<dim3(64, NCH - 1), 256, 0, stream>>>(
      x, dtT, dxT, BC, f_A_log, b_A_log, Sch, Bch);
  scan_fix<<<512, 256, 0, stream>>>(x, f_A_log, b_A_log, Sch, Bch);
  scan_pass2<<<dim3(64, NCH), 256, 0, stream>>>(
      x, dtT, dxT, BC, xc, xz, f_A_log, f_Dp, b_A_log, b_Dp, Bch, y);
  outproj_kernel<<<dim3(128, 2), 256, 0, stream>>>(y, wb, op);
  ln2_final_kernel<<<128, 256, 0, stream>>>(
      x, op, wb, ln2_g, ln2_b, b2, d_out);
}